// Round 1
// baseline (16736.258 us; speedup 1.0000x reference)
//
#include <hip/hip_runtime.h>
#include <hip/hip_bf16.h>

// ---------------------------------------------------------------------------
// DIORA inside-outside chart on MI355X.
// T=32 tokens, B=64 batch, D=768. tri=528 cells, [cell][b][d] layout.
// Level-l cells are contiguous starting at lvl_off(l).
// Compose MLP GEMMs run in bf16 MFMA (f32 accum); score path stays f32.
// Bilinear factored: score = dot(l, U[r]) with U[cell] = Wb @ inside_vec[cell].
// ---------------------------------------------------------------------------

#define T_ 32
#define D_ 768
#define TRI 528
#define MAXM 63488  // outside len=1: S=32,C=31 -> 992 pairs * 64 batch

typedef __attribute__((ext_vector_type(8))) short bf16x8;
typedef __attribute__((ext_vector_type(4))) float f32x4;

__device__ __host__ __forceinline__ int lvl_off(int l) {
    int r = 33 - l;
    return 528 - ((r * (r + 1)) >> 1);
}

__device__ __forceinline__ float bf2f(unsigned short u) {
    union { unsigned int i; float f; } v;
    v.i = ((unsigned int)u) << 16;
    return v.f;
}
__device__ __forceinline__ unsigned short f2bf(float f) {
    union { float f; unsigned int i; } v;
    v.f = f;
    unsigned int r = v.i + 0x7fffu + ((v.i >> 16) & 1u);  // RNE
    return (unsigned short)(r >> 16);
}

// ---------------------------------------------------------------------------
// Generic 64x64-tile bf16 MFMA GEMM, 256 threads (4 waves, each 32x32).
// A gathered per AMODE, B = weights bf16 [N][K] (i.e. W[n][k], so C = A @ W^T).
// AMODE 0: A = Af + row*768 (f32)              (word emb / U-gemm)
// AMODE 1: inside concat [left,right] from chart_in (f32)
// AMODE 2: outside concat [parent,sister] from chart_out/chart_in (f32)
// AMODE 3: A = Ah (bf16 H buffer)
// EPI 0: bf16(relu(acc + bias)) -> outH
// EPI 1: bf16(acc)              -> outH   (U chart)
// EPI 2: tanhf(acc + bias)      -> outF   (word linear)
// ---------------------------------------------------------------------------
template <int AMODE, int EPI>
__launch_bounds__(256)
__global__ void gemm_k(const float* __restrict__ Af,
                       const unsigned short* __restrict__ Ah,
                       const float* __restrict__ cin,
                       const float* __restrict__ cout,
                       const unsigned short* __restrict__ Bw,
                       const float* __restrict__ bias,
                       float* __restrict__ outF,
                       unsigned short* __restrict__ outH,
                       int K, int len, int C) {
    __shared__ short As[64 * 40];  // 64 rows x (32 + 8 pad)
    __shared__ short Bs[64 * 40];

    const int t = threadIdx.x;
    const int m0 = blockIdx.x << 6, n0 = blockIdx.y << 6;
    const int wv = t >> 6, lane = t & 63;
    const int wr = (wv >> 1) << 5, wc = (wv & 1) << 5;
    const int lr = lane & 15, kg = lane >> 4;

    f32x4 acc00{}, acc01{}, acc10{}, acc11{};

    const int arr = t >> 3;        // 0..31
    const int akk = (t & 7) << 2;  // 0,4,...,28
    const int bnn = t >> 2;        // 0..63
    const int bkk = (t & 3) << 3;  // 0,8,16,24

    for (int k0 = 0; k0 < K; k0 += 32) {
        // stage B tile: Bs[n][k] <- Bw[n0+n][k0+k]
        {
            const unsigned short* src = Bw + (size_t)(n0 + bnn) * K + k0 + bkk;
            *reinterpret_cast<uint4*>(&Bs[bnn * 40 + bkk]) =
                *reinterpret_cast<const uint4*>(src);
        }
        // stage A tile (2 passes of 32 rows)
#pragma unroll
        for (int pass = 0; pass < 2; ++pass) {
            const int rr = pass * 32 + arr;
            const int row = m0 + rr;
            if (AMODE == 3) {
                const unsigned short* srch = Ah + (size_t)row * 768 + k0 + akk;
                *reinterpret_cast<uint2*>(&As[rr * 40 + akk]) =
                    *reinterpret_cast<const uint2*>(srch);
            } else {
                const float* src;
                if (AMODE == 0) {
                    src = Af + (size_t)row * 768 + k0 + akk;
                } else {
                    const int p = row >> 6, b = row & 63;
                    const int s = p / C, c = p - s * C;
                    int kloc = k0 + akk;
                    if (AMODE == 1) {
                        const int j = c + 1;
                        int cell;
                        if (kloc < 768) {
                            cell = lvl_off(j) + s;                    // left child
                        } else {
                            cell = lvl_off(len - j) + s + j;          // right child
                            kloc -= 768;
                        }
                        src = cin + ((size_t)cell * 64 + b) * 768 + kloc;
                    } else {  // AMODE 2
                        if (kloc < 768) {  // parent (outside chart)
                            const int cell = (c < s)
                                ? (lvl_off(len + c + 1) + (s - c - 1))
                                : (lvl_off(len + C - c) + s);
                            src = cout + ((size_t)cell * 64 + b) * 768 + kloc;
                        } else {           // sister (inside chart)
                            const int cell = (c < s)
                                ? (lvl_off(c + 1) + (s - c - 1))
                                : (lvl_off(C - c) + (s + len));
                            src = cin + ((size_t)cell * 64 + b) * 768 + (kloc - 768);
                        }
                    }
                }
                float4 v = *reinterpret_cast<const float4*>(src);
                ushort4 h;
                h.x = f2bf(v.x); h.y = f2bf(v.y); h.z = f2bf(v.z); h.w = f2bf(v.w);
                *reinterpret_cast<ushort4*>(&As[rr * 40 + akk]) = h;
            }
        }
        __syncthreads();

        bf16x8 a0 = *reinterpret_cast<const bf16x8*>(&As[(wr + lr) * 40 + kg * 8]);
        bf16x8 a1 = *reinterpret_cast<const bf16x8*>(&As[(wr + 16 + lr) * 40 + kg * 8]);
        bf16x8 b0 = *reinterpret_cast<const bf16x8*>(&Bs[(wc + lr) * 40 + kg * 8]);
        bf16x8 b1 = *reinterpret_cast<const bf16x8*>(&Bs[(wc + 16 + lr) * 40 + kg * 8]);
        acc00 = __builtin_amdgcn_mfma_f32_16x16x32_bf16(a0, b0, acc00, 0, 0, 0);
        acc01 = __builtin_amdgcn_mfma_f32_16x16x32_bf16(a0, b1, acc01, 0, 0, 0);
        acc10 = __builtin_amdgcn_mfma_f32_16x16x32_bf16(a1, b0, acc10, 0, 0, 0);
        acc11 = __builtin_amdgcn_mfma_f32_16x16x32_bf16(a1, b1, acc11, 0, 0, 0);
        __syncthreads();
    }

    // epilogue: row = m0+wr+fm*16+kg*4+r, col = n0+wc+fn*16+lr
    const int orow = m0 + wr + (kg << 2);
    const int ocol = n0 + wc + lr;
    float bias0 = 0.f, bias1 = 0.f;
    if (EPI != 1) { bias0 = bias[ocol]; bias1 = bias[ocol + 16]; }
#pragma unroll
    for (int fm = 0; fm < 2; ++fm) {
        const f32x4 A0 = fm ? acc10 : acc00;
        const f32x4 A1 = fm ? acc11 : acc01;
#pragma unroll
        for (int r = 0; r < 4; ++r) {
            const size_t row = (size_t)(orow + fm * 16 + r) * 768;
            float v0 = A0[r], v1 = A1[r];
            if (EPI == 0) {
                v0 = fmaxf(v0 + bias0, 0.f);
                v1 = fmaxf(v1 + bias1, 0.f);
                outH[row + ocol] = f2bf(v0);
                outH[row + ocol + 16] = f2bf(v1);
            } else if (EPI == 1) {
                outH[row + ocol] = f2bf(v0);
                outH[row + ocol + 16] = f2bf(v1);
            } else {
                outF[row + ocol] = tanhf(v0 + bias0);
                outF[row + ocol + 16] = tanhf(v1 + bias1);
            }
        }
    }
}

// ---------------------------------------------------------------------------
// Per-pair raw score: dot(Lvec, U[r]) + child/parent scores. One wave per row.
// ---------------------------------------------------------------------------
template <int OUTSIDE>
__launch_bounds__(256)
__global__ void score_k(const float* __restrict__ cin, const float* __restrict__ cout,
                        const unsigned short* __restrict__ U,
                        const float* __restrict__ isc, const float* __restrict__ osc,
                        float* __restrict__ raw, int len, int C) {
    const int row = blockIdx.x * 4 + (threadIdx.x >> 6);
    const int lane = threadIdx.x & 63;
    const int p = row >> 6, b = row & 63;
    const int s = p / C, c = p - s * C;
    const float* L;
    const unsigned short* Uv;
    float sadd;
    if (!OUTSIDE) {
        const int j = c + 1;
        const int cl = lvl_off(j) + s;
        const int cr = lvl_off(len - j) + s + j;
        L = cin + ((size_t)cl * 64 + b) * 768;
        Uv = U + ((size_t)cr * 64 + b) * 768;
        sadd = isc[cl * 64 + b] + isc[cr * 64 + b];
    } else {
        int cl, cr;
        if (c < s) { cl = lvl_off(len + c + 1) + (s - c - 1); cr = lvl_off(c + 1) + (s - c - 1); }
        else       { cl = lvl_off(len + C - c) + s;           cr = lvl_off(C - c) + (s + len); }
        L = cout + ((size_t)cl * 64 + b) * 768;
        Uv = U + ((size_t)cr * 64 + b) * 768;
        sadd = osc[cl * 64 + b] + isc[cr * 64 + b];
    }
    float d = 0.f;
#pragma unroll
    for (int it = 0; it < 3; ++it) {
        const int i = lane * 4 + it * 256;
        float4 lv = *reinterpret_cast<const float4*>(&L[i]);
        ushort4 uv = *reinterpret_cast<const ushort4*>(&Uv[i]);
        d += lv.x * bf2f(uv.x) + lv.y * bf2f(uv.y) + lv.z * bf2f(uv.z) + lv.w * bf2f(uv.w);
    }
#pragma unroll
    for (int o = 32; o; o >>= 1) d += __shfl_xor(d, o);
    if (lane == 0) raw[row] = d + sadd;
}

// softmax over C contexts per (span, batch); writes weights + weighted score.
__launch_bounds__(256)
__global__ void softmax_k(const float* __restrict__ raw, float* __restrict__ w,
                          float* __restrict__ cscore, int C, int S) {
    const int idx = blockIdx.x * 256 + threadIdx.x;
    if (idx >= S * 64) return;
    const int s = idx >> 6, b = idx & 63;
    float m = -1e30f;
    for (int c = 0; c < C; ++c) m = fmaxf(m, raw[((s * C + c) << 6) + b]);
    float sum = 0.f;
    for (int c = 0; c < C; ++c) sum += expf(raw[((s * C + c) << 6) + b] - m);
    const float inv = 1.f / sum;
    float osum = 0.f;
    for (int c = 0; c < C; ++c) {
        const float x = raw[((s * C + c) << 6) + b];
        const float wv = expf(x - m) * inv;
        w[((s * C + c) << 6) + b] = wv;
        osum += wv * x;
    }
    cscore[idx] = osum;
}

// weighted sum over contexts + L2-normalize -> chart level block.
__launch_bounds__(256)
__global__ void reduce_norm_k(const unsigned short* __restrict__ V,
                              const float* __restrict__ w,
                              float* __restrict__ outv, int C) {
    __shared__ float red[256];
    const int sb = blockIdx.x;
    const int s = sb >> 6, b = sb & 63;
    const int t = threadIdx.x;
    float a0 = 0.f, a1 = 0.f, a2 = 0.f;
    for (int c = 0; c < C; ++c) {
        const int rowi = ((s * C + c) << 6) + b;
        const float wv = w[rowi];
        const unsigned short* vp = V + (size_t)rowi * 768;
        a0 += wv * bf2f(vp[t]);
        a1 += wv * bf2f(vp[t + 256]);
        a2 += wv * bf2f(vp[t + 512]);
    }
    red[t] = a0 * a0 + a1 * a1 + a2 * a2;
    __syncthreads();
    for (int o = 128; o; o >>= 1) {
        if (t < o) red[t] += red[t + o];
        __syncthreads();
    }
    const float scale = 1.f / fmaxf(sqrtf(red[0]), 1e-12f);
    float* out = outv + (size_t)sb * 768;
    out[t] = a0 * scale;
    out[t + 256] = a1 * scale;
    out[t + 512] = a2 * scale;
}

// in-place row L2-normalize (word level)
__launch_bounds__(256)
__global__ void norm_rows_k(float* __restrict__ base) {
    __shared__ float red[256];
    float* p = base + (size_t)blockIdx.x * 768;
    const int t = threadIdx.x;
    const float a0 = p[t], a1 = p[t + 256], a2 = p[t + 512];
    red[t] = a0 * a0 + a1 * a1 + a2 * a2;
    __syncthreads();
    for (int o = 128; o; o >>= 1) {
        if (t < o) red[t] += red[t + o];
        __syncthreads();
    }
    const float scale = 1.f / fmaxf(sqrtf(red[0]), 1e-12f);
    p[t] = a0 * scale;
    p[t + 256] = a1 * scale;
    p[t + 512] = a2 * scale;
}

// root cell: normalize(root_bias) broadcast over batch.
__launch_bounds__(256)
__global__ void root_k(const float* __restrict__ rb, float* __restrict__ cout) {
    __shared__ float red[256];
    const int t = threadIdx.x;
    const float a0 = rb[t], a1 = rb[t + 256], a2 = rb[t + 512];
    red[t] = a0 * a0 + a1 * a1 + a2 * a2;
    __syncthreads();
    for (int o = 128; o; o >>= 1) {
        if (t < o) red[t] += red[t + o];
        __syncthreads();
    }
    const float scale = 1.f / fmaxf(sqrtf(red[0]), 1e-12f);
    const float v0 = a0 * scale, v1 = a1 * scale, v2 = a2 * scale;
    for (int b = 0; b < 64; ++b) {
        float* o = cout + ((size_t)(527 * 64 + b)) * 768;
        o[t] = v0; o[t + 256] = v1; o[t + 512] = v2;
    }
}

__launch_bounds__(256)
__global__ void cvt_bf16_k(const float* __restrict__ src,
                           unsigned short* __restrict__ dst, int n) {
    const int i = blockIdx.x * 256 + threadIdx.x;
    if (i < n) dst[i] = f2bf(src[i]);
}

// out[cell][b] = [in_vec(768) | out_vec(768) | in_score | out_score]
__launch_bounds__(256)
__global__ void assemble_k(const float* __restrict__ cin, const float* __restrict__ cout,
                           const float* __restrict__ isc, const float* __restrict__ osc,
                           float* __restrict__ out) {
    const int sb = blockIdx.x;
    const int t = threadIdx.x;
    const float* iv = cin + (size_t)sb * 768;
    const float* ov = cout + (size_t)sb * 768;
    float* o = out + (size_t)sb * 1538;
    o[t] = iv[t]; o[t + 256] = iv[t + 256]; o[t + 512] = iv[t + 512];
    o[768 + t] = ov[t]; o[768 + t + 256] = ov[t + 256]; o[768 + t + 512] = ov[t + 512];
    if (t == 0) { o[1536] = isc[sb]; o[1537] = osc[sb]; }
}

// ---------------------------------------------------------------------------
extern "C" void kernel_launch(void* const* d_in, const int* in_sizes, int n_in,
                              void* d_out, int out_size, void* d_ws, size_t ws_size,
                              hipStream_t stream) {
    const float* emb = (const float*)d_in[0];
    const float* Wl = (const float*)d_in[1];
    const float* bl = (const float*)d_in[2];
    const float* W1 = (const float*)d_in[3];
    const float* b1 = (const float*)d_in[4];
    const float* W2 = (const float*)d_in[5];
    const float* b2 = (const float*)d_in[6];
    const float* Wb = (const float*)d_in[7];
    const float* rb = (const float*)d_in[8];
    float* out = (float*)d_out;

    char* ws = (char*)d_ws;
    size_t off = 0;
    auto alloc = [&](size_t bytes) {
        char* p = ws + off;
        off = (off + bytes + 255) & ~(size_t)255;
        return p;
    };
    float* chart_in = (float*)alloc((size_t)TRI * 64 * 768 * 4);
    float* chart_out = (float*)alloc((size_t)TRI * 64 * 768 * 4);
    unsigned short* Uh = (unsigned short*)alloc((size_t)TRI * 64 * 768 * 2);
    unsigned short* Hh = (unsigned short*)alloc((size_t)MAXM * 768 * 2);
    unsigned short* Vh = (unsigned short*)alloc((size_t)MAXM * 768 * 2);
    float* chart_is = (float*)alloc((size_t)TRI * 64 * 4);
    float* chart_os = (float*)alloc((size_t)TRI * 64 * 4);
    float* raw = (float*)alloc((size_t)MAXM * 4);
    float* wbuf = (float*)alloc((size_t)MAXM * 4);
    unsigned short* Wlh = (unsigned short*)alloc((size_t)768 * 768 * 2);
    unsigned short* W1h = (unsigned short*)alloc((size_t)768 * 1536 * 2);
    unsigned short* W2h = (unsigned short*)alloc((size_t)768 * 768 * 2);
    unsigned short* Wbh = (unsigned short*)alloc((size_t)768 * 768 * 2);

    // weights -> bf16 (layout unchanged: [n][k])
    cvt_bf16_k<<<(768 * 768 + 255) / 256, 256, 0, stream>>>(Wl, Wlh, 768 * 768);
    cvt_bf16_k<<<(768 * 1536 + 255) / 256, 256, 0, stream>>>(W1, W1h, 768 * 1536);
    cvt_bf16_k<<<(768 * 768 + 255) / 256, 256, 0, stream>>>(W2, W2h, 768 * 768);
    cvt_bf16_k<<<(768 * 768 + 255) / 256, 256, 0, stream>>>(Wb, Wbh, 768 * 768);
    hipMemsetAsync(chart_is, 0, (size_t)TRI * 64 * 4, stream);
    hipMemsetAsync(chart_os, 0, (size_t)TRI * 64 * 4, stream);

    // word level: tanh(emb @ Wl^T + bl) -> normalize; then U for level 1
    gemm_k<0, 2><<<dim3(2048 / 64, 12), 256, 0, stream>>>(
        emb, nullptr, nullptr, nullptr, Wlh, bl, chart_in, nullptr, 768, 0, 0);
    norm_rows_k<<<2048, 256, 0, stream>>>(chart_in);
    gemm_k<0, 1><<<dim3(2048 / 64, 12), 256, 0, stream>>>(
        chart_in, nullptr, nullptr, nullptr, Wbh, nullptr, nullptr, Uh, 768, 0, 0);

    // ---------------- inside pass ----------------
    for (int len = 2; len <= 32; ++len) {
        const int S = 33 - len, C = len - 1, M = S * C * 64;
        const size_t lo = (size_t)lvl_off(len);
        score_k<0><<<M / 4, 256, 0, stream>>>(chart_in, nullptr, Uh, chart_is, nullptr,
                                              raw, len, C);
        softmax_k<<<(S * 64 + 255) / 256, 256, 0, stream>>>(raw, wbuf,
                                                            chart_is + lo * 64, C, S);
        gemm_k<1, 0><<<dim3(M / 64, 12), 256, 0, stream>>>(
            nullptr, nullptr, chart_in, nullptr, W1h, b1, nullptr, Hh, 1536, len, C);
        gemm_k<3, 0><<<dim3(M / 64, 12), 256, 0, stream>>>(
            nullptr, Hh, nullptr, nullptr, W2h, b2, nullptr, Vh, 768, 0, 0);
        reduce_norm_k<<<S * 64, 256, 0, stream>>>(Vh, wbuf,
                                                  chart_in + lo * 64 * 768, C);
        gemm_k<0, 1><<<dim3(S * 64 / 64, 12), 256, 0, stream>>>(
            chart_in + lo * 64 * 768, nullptr, nullptr, nullptr, Wbh, nullptr, nullptr,
            Uh + lo * 64 * 768, 768, 0, 0);
    }

    // ---------------- outside pass ----------------
    root_k<<<1, 256, 0, stream>>>(rb, chart_out);
    for (int len = 31; len >= 1; --len) {
        const int S = 33 - len, C = 32 - len, M = S * C * 64;
        const size_t lo = (size_t)lvl_off(len);
        score_k<1><<<M / 4, 256, 0, stream>>>(chart_in, chart_out, Uh, chart_is,
                                              chart_os, raw, len, C);
        softmax_k<<<(S * 64 + 255) / 256, 256, 0, stream>>>(raw, wbuf,
                                                            chart_os + lo * 64, C, S);
        gemm_k<2, 0><<<dim3(M / 64, 12), 256, 0, stream>>>(
            nullptr, nullptr, chart_in, chart_out, W1h, b1, nullptr, Hh, 1536, len, C);
        gemm_k<3, 0><<<dim3(M / 64, 12), 256, 0, stream>>>(
            nullptr, Hh, nullptr, nullptr, W2h, b2, nullptr, Vh, 768, 0, 0);
        reduce_norm_k<<<S * 64, 256, 0, stream>>>(Vh, wbuf,
                                                  chart_out + lo * 64 * 768, C);
    }

    assemble_k<<<TRI * 64, 256, 0, stream>>>(chart_in, chart_out, chart_is, chart_os,
                                             out);
}

// Round 3
// 8442.671 us; speedup vs baseline: 1.9823x; 1.9823x over previous
//
#include <hip/hip_runtime.h>
#include <hip/hip_bf16.h>

// ---------------------------------------------------------------------------
// DIORA inside-outside chart on MI355X — all-bf16 chart storage.
// T=32, B=64, D=768, tri=528 cells, [cell][b][d] layout, bf16 vectors.
// GEMM: BM=64 (one pair/block), BN=128, BK=64, global_load_lds(16B) staging
// with XOR swizzle (byte ^= (row&7)<<4) applied on the pre-swizzled global
// source (linear LDS dest) and on ds_read_b128 fragment reads.
// ---------------------------------------------------------------------------

#define TRI 528
#define MAXM 63488  // outside len=1: 992 pairs * 64 batch

typedef __attribute__((ext_vector_type(8))) short bf16x8;
typedef __attribute__((ext_vector_type(4))) float f32x4;

__device__ __host__ __forceinline__ int lvl_off(int l) {
    int r = 33 - l;
    return 528 - ((r * (r + 1)) >> 1);
}

__device__ __forceinline__ float bf2f(unsigned short u) {
    union { unsigned int i; float f; } v;
    v.i = ((unsigned int)u) << 16;
    return v.f;
}
__device__ __forceinline__ unsigned short f2bf(float f) {
    union { float f; unsigned int i; } v;
    v.f = f;
    unsigned int r = v.i + 0x7fffu + ((v.i >> 16) & 1u);  // RNE
    return (unsigned short)(r >> 16);
}

__device__ __forceinline__ void gload16(const unsigned short* g, unsigned short* l) {
    __builtin_amdgcn_global_load_lds(
        (const __attribute__((address_space(1))) unsigned int*)g,
        (__attribute__((address_space(3))) unsigned int*)l, 16, 0, 0);
}

__device__ __forceinline__ const bf16x8* frag_ptr(const unsigned short* base,
                                                  int row, int kelem) {
    const int byte = (row * 128 + kelem * 2) ^ ((row & 7) << 4);
    return reinterpret_cast<const bf16x8*>(reinterpret_cast<const char*>(base) + byte);
}

// ---------------------------------------------------------------------------
// bf16 MFMA GEMM, C = A @ W^T.  BM=64, BN=128, BK=64, 256 threads (4 waves,
// each 32x64). Weights Bw: bf16 [N][K]. A per AMODE:
//   0: plain bf16 rows, stride K (embH / chartH level block / Hh)
//   1: inside concat  [left(chartH_in) | right(chartH_in)]
//   2: outside concat [parent(chartH_out) | sister(chartH_in)]
// EPI 0: bf16(relu(acc+bias)) -> outH ; 1: bf16(acc) -> outH ;
// EPI 2: tanhf(acc+bias) -> outF (f32, word level).
// ---------------------------------------------------------------------------
template <int AMODE, int EPI>
__launch_bounds__(256)
__global__ void gemm_k(const unsigned short* __restrict__ Abase,
                       const unsigned short* __restrict__ cinH,
                       const unsigned short* __restrict__ coutH,
                       const unsigned short* __restrict__ Bw,
                       const float* __restrict__ bias,
                       float* __restrict__ outF,
                       unsigned short* __restrict__ outH,
                       int K, int len, int C) {
    __shared__ unsigned short As[64 * 64];    // 8 KB, linear, source-swizzled
    __shared__ unsigned short Bs[128 * 64];   // 16 KB

    const int t = threadIdx.x;
    const int m0 = blockIdx.x << 6;
    const int n0 = blockIdx.y << 7;

    // staging geometry: LDS byte slot p = i*4096 + t*16 ; row = p>>7 ;
    // source column byte = (p&127) ^ ((row&7)<<4)   (swizzle on the source)
    int arow[2], acol[2];
#pragma unroll
    for (int i = 0; i < 2; ++i) {
        const int p = (i << 12) + t * 16;
        const int r = p >> 7;
        arow[i] = r;
        acol[i] = ((p & 127) ^ ((r & 7) << 4)) >> 1;  // element offset
    }
    int brow[4], bcol[4];
#pragma unroll
    for (int i = 0; i < 4; ++i) {
        const int p = (i << 12) + t * 16;
        const int r = p >> 7;
        brow[i] = r;
        bcol[i] = ((p & 127) ^ ((r & 7) << 4)) >> 1;
    }

    // A gather bases (block-uniform cells; row==batch index b)
    const unsigned short *aL[2], *aR[2];
    if (AMODE == 1 || AMODE == 2) {
        const int p = blockIdx.x;
        const int s = p / C, c = p - s * C;
        int cl, cr;
        if (AMODE == 1) {
            const int j = c + 1;
            cl = lvl_off(j) + s;
            cr = lvl_off(len - j) + s + j;
        } else {
            if (c < s) { cl = lvl_off(len + c + 1) + (s - c - 1); cr = lvl_off(c + 1) + (s - c - 1); }
            else       { cl = lvl_off(len + C - c) + s;           cr = lvl_off(C - c) + (s + len); }
        }
#pragma unroll
        for (int i = 0; i < 2; ++i) {
            const int b = arow[i];
            aL[i] = (AMODE == 1 ? cinH : coutH) + ((size_t)cl * 64 + b) * 768;
            aR[i] = cinH + ((size_t)cr * 64 + b) * 768;
        }
    }

    const int wv = t >> 6, lane = t & 63;
    const int lr = lane & 15, kg = lane >> 4;
    const int wr = (wv >> 1) << 5;   // 0 / 32
    const int wc = (wv & 1) << 6;    // 0 / 64

    f32x4 acc[2][4] = {};

    for (int k0 = 0; k0 < K; k0 += 64) {
        // ---- stage A (2 x 4KB) and B (4 x 4KB) via global_load_lds ----
#pragma unroll
        for (int i = 0; i < 2; ++i) {
            const unsigned short* src;
            if (AMODE == 0) {
                src = Abase + (size_t)(m0 + arow[i]) * K + k0 + acol[i];
            } else {
                src = (k0 < 768 ? aL[i] + k0 : aR[i] + (k0 - 768)) + acol[i];
            }
            gload16(src, &As[(i << 11) + t * 8]);
        }
#pragma unroll
        for (int i = 0; i < 4; ++i) {
            const unsigned short* src = Bw + (size_t)(n0 + brow[i]) * K + k0 + bcol[i];
            gload16(src, &Bs[(i << 11) + t * 8]);
        }
        __syncthreads();  // drains vmcnt(0): LDS tiles ready

        // ---- MFMA: 2 k-subtiles of 32 ----
#pragma unroll
        for (int kk = 0; kk < 2; ++kk) {
            const int ke = kk * 32 + kg * 8;
            const bf16x8 a0 = *frag_ptr(As, wr + lr, ke);
            const bf16x8 a1 = *frag_ptr(As, wr + 16 + lr, ke);
            const bf16x8 b0 = *frag_ptr(Bs, wc + lr, ke);
            const bf16x8 b1 = *frag_ptr(Bs, wc + 16 + lr, ke);
            const bf16x8 b2 = *frag_ptr(Bs, wc + 32 + lr, ke);
            const bf16x8 b3 = *frag_ptr(Bs, wc + 48 + lr, ke);
            acc[0][0] = __builtin_amdgcn_mfma_f32_16x16x32_bf16(a0, b0, acc[0][0], 0, 0, 0);
            acc[0][1] = __builtin_amdgcn_mfma_f32_16x16x32_bf16(a0, b1, acc[0][1], 0, 0, 0);
            acc[0][2] = __builtin_amdgcn_mfma_f32_16x16x32_bf16(a0, b2, acc[0][2], 0, 0, 0);
            acc[0][3] = __builtin_amdgcn_mfma_f32_16x16x32_bf16(a0, b3, acc[0][3], 0, 0, 0);
            acc[1][0] = __builtin_amdgcn_mfma_f32_16x16x32_bf16(a1, b0, acc[1][0], 0, 0, 0);
            acc[1][1] = __builtin_amdgcn_mfma_f32_16x16x32_bf16(a1, b1, acc[1][1], 0, 0, 0);
            acc[1][2] = __builtin_amdgcn_mfma_f32_16x16x32_bf16(a1, b2, acc[1][2], 0, 0, 0);
            acc[1][3] = __builtin_amdgcn_mfma_f32_16x16x32_bf16(a1, b3, acc[1][3], 0, 0, 0);
        }
        __syncthreads();  // all waves done reading before next stage
    }

    // ---- epilogue: row = m0+wr+fm*16+kg*4+r, col = n0+wc+fn*16+lr ----
    float bs[4];
    if (EPI != 1) {
#pragma unroll
        for (int fn = 0; fn < 4; ++fn) bs[fn] = bias[n0 + wc + fn * 16 + lr];
    }
#pragma unroll
    for (int fm = 0; fm < 2; ++fm) {
#pragma unroll
        for (int fn = 0; fn < 4; ++fn) {
#pragma unroll
            for (int r = 0; r < 4; ++r) {
                const size_t row = (size_t)(m0 + wr + fm * 16 + (kg << 2) + r) * 768;
                const int col = n0 + wc + fn * 16 + lr;
                float v = acc[fm][fn][r];
                if (EPI == 0) {
                    outH[row + col] = f2bf(fmaxf(v + bs[fn], 0.f));
                } else if (EPI == 1) {
                    outH[row + col] = f2bf(v);
                } else {
                    outF[row + col] = tanhf(v + bs[fn]);
                }
            }
        }
    }
}

// ---------------------------------------------------------------------------
// Per-pair raw score: dot(L, U[r]) + child/parent scores. Wave per row.
// ---------------------------------------------------------------------------
template <int OUTSIDE>
__launch_bounds__(256)
__global__ void score_k(const unsigned short* __restrict__ cinH,
                        const unsigned short* __restrict__ coutH,
                        const unsigned short* __restrict__ U,
                        const float* __restrict__ isc, const float* __restrict__ osc,
                        float* __restrict__ raw, int len, int C) {
    const int row = blockIdx.x * 4 + (threadIdx.x >> 6);
    const int lane = threadIdx.x & 63;
    const int p = row >> 6, b = row & 63;
    const int s = p / C, c = p - s * C;
    int cl, cr;
    float sadd;
    const unsigned short* L;
    if (!OUTSIDE) {
        const int j = c + 1;
        cl = lvl_off(j) + s;
        cr = lvl_off(len - j) + s + j;
        L = cinH + ((size_t)cl * 64 + b) * 768;
        sadd = isc[cl * 64 + b] + isc[cr * 64 + b];
    } else {
        if (c < s) { cl = lvl_off(len + c + 1) + (s - c - 1); cr = lvl_off(c + 1) + (s - c - 1); }
        else       { cl = lvl_off(len + C - c) + s;           cr = lvl_off(C - c) + (s + len); }
        L = coutH + ((size_t)cl * 64 + b) * 768;
        sadd = osc[cl * 64 + b] + isc[cr * 64 + b];
    }
    const unsigned short* Uv = U + ((size_t)cr * 64 + b) * 768;
    float d = 0.f;
#pragma unroll
    for (int it = 0; it < 3; ++it) {
        const int i = lane * 4 + it * 256;
        ushort4 lv = *reinterpret_cast<const ushort4*>(&L[i]);
        ushort4 uv = *reinterpret_cast<const ushort4*>(&Uv[i]);
        d += bf2f(lv.x) * bf2f(uv.x) + bf2f(lv.y) * bf2f(uv.y) +
             bf2f(lv.z) * bf2f(uv.z) + bf2f(lv.w) * bf2f(uv.w);
    }
#pragma unroll
    for (int o = 32; o; o >>= 1) d += __shfl_xor(d, o);
    if (lane == 0) raw[row] = d + sadd;
}

// softmax over C contexts per (span, batch); writes weights + weighted score.
__launch_bounds__(256)
__global__ void softmax_k(const float* __restrict__ raw, float* __restrict__ w,
                          float* __restrict__ cscore, int C, int S) {
    const int idx = blockIdx.x * 256 + threadIdx.x;
    if (idx >= S * 64) return;
    const int s = idx >> 6, b = idx & 63;
    float m = -1e30f;
    for (int c = 0; c < C; ++c) m = fmaxf(m, raw[((s * C + c) << 6) + b]);
    float sum = 0.f;
    for (int c = 0; c < C; ++c) sum += expf(raw[((s * C + c) << 6) + b] - m);
    const float inv = 1.f / sum;
    float osum = 0.f;
    for (int c = 0; c < C; ++c) {
        const float x = raw[((s * C + c) << 6) + b];
        const float wv = expf(x - m) * inv;
        w[((s * C + c) << 6) + b] = wv;
        osum += wv * x;
    }
    cscore[idx] = osum;
}

// weighted sum over contexts + L2-normalize -> bf16 chart level block.
__launch_bounds__(256)
__global__ void reduce_norm_k(const unsigned short* __restrict__ V,
                              const float* __restrict__ w,
                              unsigned short* __restrict__ outvH, int C) {
    __shared__ float red[256];
    const int sb = blockIdx.x;
    const int s = sb >> 6, b = sb & 63;
    const int t = threadIdx.x;
    float a0 = 0.f, a1 = 0.f, a2 = 0.f;
    for (int c = 0; c < C; ++c) {
        const int rowi = ((s * C + c) << 6) + b;
        const float wv = w[rowi];
        const unsigned short* vp = V + (size_t)rowi * 768;
        a0 += wv * bf2f(vp[t]);
        a1 += wv * bf2f(vp[t + 256]);
        a2 += wv * bf2f(vp[t + 512]);
    }
    red[t] = a0 * a0 + a1 * a1 + a2 * a2;
    __syncthreads();
    for (int o = 128; o; o >>= 1) {
        if (t < o) red[t] += red[t + o];
        __syncthreads();
    }
    const float scale = 1.f / fmaxf(sqrtf(red[0]), 1e-12f);
    unsigned short* out = outvH + (size_t)sb * 768;
    out[t] = f2bf(a0 * scale);
    out[t + 256] = f2bf(a1 * scale);
    out[t + 512] = f2bf(a2 * scale);
}

// row L2-normalize f32 src -> bf16 dst (word level)
__launch_bounds__(256)
__global__ void norm_rows_k(const float* __restrict__ src,
                            unsigned short* __restrict__ dstH) {
    __shared__ float red[256];
    const float* p = src + (size_t)blockIdx.x * 768;
    const int t = threadIdx.x;
    const float a0 = p[t], a1 = p[t + 256], a2 = p[t + 512];
    red[t] = a0 * a0 + a1 * a1 + a2 * a2;
    __syncthreads();
    for (int o = 128; o; o >>= 1) {
        if (t < o) red[t] += red[t + o];
        __syncthreads();
    }
    const float scale = 1.f / fmaxf(sqrtf(red[0]), 1e-12f);
    unsigned short* d = dstH + (size_t)blockIdx.x * 768;
    d[t] = f2bf(a0 * scale);
    d[t + 256] = f2bf(a1 * scale);
    d[t + 512] = f2bf(a2 * scale);
}

// root cell: normalize(root_bias) broadcast over batch (bf16).
__launch_bounds__(256)
__global__ void root_k(const float* __restrict__ rb,
                       unsigned short* __restrict__ coutH) {
    __shared__ float red[256];
    const int t = threadIdx.x;
    const float a0 = rb[t], a1 = rb[t + 256], a2 = rb[t + 512];
    red[t] = a0 * a0 + a1 * a1 + a2 * a2;
    __syncthreads();
    for (int o = 128; o; o >>= 1) {
        if (t < o) red[t] += red[t + o];
        __syncthreads();
    }
    const float scale = 1.f / fmaxf(sqrtf(red[0]), 1e-12f);
    const unsigned short v0 = f2bf(a0 * scale), v1 = f2bf(a1 * scale),
                         v2 = f2bf(a2 * scale);
    for (int b = 0; b < 64; ++b) {
        unsigned short* o = coutH + ((size_t)(527 * 64 + b)) * 768;
        o[t] = v0; o[t + 256] = v1; o[t + 512] = v2;
    }
}

__launch_bounds__(256)
__global__ void cvt_bf16_k(const float* __restrict__ src,
                           unsigned short* __restrict__ dst, int n) {
    const int i = blockIdx.x * 256 + threadIdx.x;
    if (i < n) dst[i] = f2bf(src[i]);
}

// out[cell][b] = [in_vec(768) | out_vec(768) | in_score | out_score]
__launch_bounds__(256)
__global__ void assemble_k(const unsigned short* __restrict__ cinH,
                           const unsigned short* __restrict__ coutH,
                           const float* __restrict__ isc, const float* __restrict__ osc,
                           float* __restrict__ out) {
    const int sb = blockIdx.x;
    const int t = threadIdx.x;
    const unsigned short* iv = cinH + (size_t)sb * 768;
    const unsigned short* ov = coutH + (size_t)sb * 768;
    float* o = out + (size_t)sb * 1538;
    o[t] = bf2f(iv[t]); o[t + 256] = bf2f(iv[t + 256]); o[t + 512] = bf2f(iv[t + 512]);
    o[768 + t] = bf2f(ov[t]); o[768 + t + 256] = bf2f(ov[t + 256]);
    o[768 + t + 512] = bf2f(ov[t + 512]);
    if (t == 0) { o[1536] = isc[sb]; o[1537] = osc[sb]; }
}

// ---------------------------------------------------------------------------
extern "C" void kernel_launch(void* const* d_in, const int* in_sizes, int n_in,
                              void* d_out, int out_size, void* d_ws, size_t ws_size,
                              hipStream_t stream) {
    const float* emb = (const float*)d_in[0];
    const float* Wl = (const float*)d_in[1];
    const float* bl = (const float*)d_in[2];
    const float* W1 = (const float*)d_in[3];
    const float* b1 = (const float*)d_in[4];
    const float* W2 = (const float*)d_in[5];
    const float* b2 = (const float*)d_in[6];
    const float* Wb = (const float*)d_in[7];
    const float* rb = (const float*)d_in[8];
    float* out = (float*)d_out;

    char* ws = (char*)d_ws;
    size_t off = 0;
    auto alloc = [&](size_t bytes) {
        char* p = ws + off;
        off = (off + bytes + 255) & ~(size_t)255;
        return p;
    };
    unsigned short* cinH = (unsigned short*)alloc((size_t)TRI * 64 * 768 * 2);
    unsigned short* coutH = (unsigned short*)alloc((size_t)TRI * 64 * 768 * 2);
    unsigned short* Uh = (unsigned short*)alloc((size_t)TRI * 64 * 768 * 2);
    unsigned short* Hh = (unsigned short*)alloc((size_t)MAXM * 768 * 2);
    unsigned short* Vh = (unsigned short*)alloc((size_t)MAXM * 768 * 2);
    unsigned short* embH = (unsigned short*)alloc((size_t)2048 * 768 * 2);
    float* chart_is = (float*)alloc((size_t)TRI * 64 * 4);
    float* chart_os = (float*)alloc((size_t)TRI * 64 * 4);
    float* raw = (float*)alloc((size_t)MAXM * 4);
    float* wbuf = (float*)alloc((size_t)MAXM * 4);
    unsigned short* Wlh = (unsigned short*)alloc((size_t)768 * 768 * 2);
    unsigned short* W1h = (unsigned short*)alloc((size_t)768 * 1536 * 2);
    unsigned short* W2h = (unsigned short*)alloc((size_t)768 * 768 * 2);
    unsigned short* Wbh = (unsigned short*)alloc((size_t)768 * 768 * 2);
    float* tmpF = (float*)Hh;  // word-level tanh temp (f32 view, 6MB < Hh)

    cvt_bf16_k<<<(768 * 768 + 255) / 256, 256, 0, stream>>>(Wl, Wlh, 768 * 768);
    cvt_bf16_k<<<(768 * 1536 + 255) / 256, 256, 0, stream>>>(W1, W1h, 768 * 1536);
    cvt_bf16_k<<<(768 * 768 + 255) / 256, 256, 0, stream>>>(W2, W2h, 768 * 768);
    cvt_bf16_k<<<(768 * 768 + 255) / 256, 256, 0, stream>>>(Wb, Wbh, 768 * 768);
    cvt_bf16_k<<<(2048 * 768 + 255) / 256, 256, 0, stream>>>(emb, embH, 2048 * 768);
    hipMemsetAsync(chart_is, 0, (size_t)TRI * 64 * 4, stream);
    hipMemsetAsync(chart_os, 0, (size_t)TRI * 64 * 4, stream);

    // word level: tanh(emb @ Wl^T + bl) -> f32 tmp -> normalize -> bf16 chart
    gemm_k<0, 2><<<dim3(32, 6), 256, 0, stream>>>(
        embH, nullptr, nullptr, Wlh, bl, tmpF, nullptr, 768, 0, 0);
    norm_rows_k<<<2048, 256, 0, stream>>>(tmpF, cinH);
    gemm_k<0, 1><<<dim3(32, 6), 256, 0, stream>>>(
        cinH, nullptr, nullptr, Wbh, nullptr, nullptr, Uh, 768, 0, 0);

    // ---------------- inside pass ----------------
    for (int len = 2; len <= 32; ++len) {
        const int S = 33 - len, C = len - 1, M = S * C * 64;
        const size_t lo = (size_t)lvl_off(len);
        score_k<0><<<M / 4, 256, 0, stream>>>(cinH, nullptr, Uh, chart_is, nullptr,
                                              raw, len, C);
        softmax_k<<<(S * 64 + 255) / 256, 256, 0, stream>>>(raw, wbuf,
                                                            chart_is + lo * 64, C, S);
        gemm_k<1, 0><<<dim3(M / 64, 6), 256, 0, stream>>>(
            nullptr, cinH, nullptr, W1h, b1, nullptr, Hh, 1536, len, C);
        gemm_k<0, 0><<<dim3(M / 64, 6), 256, 0, stream>>>(
            Hh, nullptr, nullptr, W2h, b2, nullptr, Vh, 768, 0, 0);
        reduce_norm_k<<<S * 64, 256, 0, stream>>>(Vh, wbuf, cinH + lo * 64 * 768, C);
        gemm_k<0, 1><<<dim3(S, 6), 256, 0, stream>>>(
            cinH + lo * 64 * 768, nullptr, nullptr, Wbh, nullptr, nullptr,
            Uh + lo * 64 * 768, 768, 0, 0);
    }

    // ---------------- outside pass ----------------
    root_k<<<1, 256, 0, stream>>>(rb, coutH);
    for (int len = 31; len >= 1; --len) {
        const int S = 33 - len, C = 32 - len, M = S * C * 64;
        const size_t lo = (size_t)lvl_off(len);
        score_k<1><<<M / 4, 256, 0, stream>>>(cinH, coutH, Uh, chart_is, chart_os,
                                              raw, len, C);
        softmax_k<<<(S * 64 + 255) / 256, 256, 0, stream>>>(raw, wbuf,
                                                            chart_os + lo * 64, C, S);
        gemm_k<2, 0><<<dim3(M / 64, 6), 256, 0, stream>>>(
            nullptr, cinH, coutH, W1h, b1, nullptr, Hh, 1536, len, C);
        gemm_k<0, 0><<<dim3(M / 64, 6), 256, 0, stream>>>(
            Hh, nullptr, nullptr, W2h, b2, nullptr, Vh, 768, 0, 0);
        reduce_norm_k<<<S * 64, 256, 0, stream>>>(Vh, wbuf, coutH + lo * 64 * 768, C);
    }

    assemble_k<<<TRI * 64, 256, 0, stream>>>(cinH, coutH, chart_is, chart_os, out);
}

// Round 5
// 8214.706 us; speedup vs baseline: 2.0374x; 1.0278x over previous
//
#include <hip/hip_runtime.h>
#include <hip/hip_bf16.h>

// ---------------------------------------------------------------------------
// DIORA inside-outside chart on MI355X — all-bf16 chart storage.
// T=32, B=64, D=768, tri=528 cells, [cell][b][d] layout, bf16 vectors.
// GEMM: BM=128 (2 pairs/block), BN=128, BK=64, 512 thr / 8 waves,
// global_load_lds(16B) staging, XOR swizzle (byte ^= (row&7)<<4) applied on
// pre-swizzled global source (linear LDS dest) and on ds_read_b128 reads.
// score+softmax fused; reduce_norm vectorized (ushort4).
// ---------------------------------------------------------------------------

#define TRI 528
#define MAXM 63488  // outside len=1: 992 pairs * 64 batch

typedef __attribute__((ext_vector_type(8))) short bf16x8;
typedef __attribute__((ext_vector_type(4))) float f32x4;

__device__ __host__ __forceinline__ int lvl_off(int l) {
    int r = 33 - l;
    return 528 - ((r * (r + 1)) >> 1);
}

__device__ __forceinline__ float bf2f(unsigned short u) {
    union { unsigned int i; float f; } v;
    v.i = ((unsigned int)u) << 16;
    return v.f;
}
__device__ __forceinline__ unsigned short f2bf(float f) {
    union { float f; unsigned int i; } v;
    v.f = f;
    unsigned int r = v.i + 0x7fffu + ((v.i >> 16) & 1u);  // RNE
    return (unsigned short)(r >> 16);
}

__device__ __forceinline__ void gload16(const unsigned short* g, unsigned short* l) {
    __builtin_amdgcn_global_load_lds(
        (const __attribute__((address_space(1))) unsigned int*)g,
        (__attribute__((address_space(3))) unsigned int*)l, 16, 0, 0);
}

__device__ __forceinline__ const bf16x8* frag_ptr(const unsigned short* base,
                                                  int row, int kelem) {
    const int byte = (row * 128 + kelem * 2) ^ ((row & 7) << 4);
    return reinterpret_cast<const bf16x8*>(reinterpret_cast<const char*>(base) + byte);
}

// ---------------------------------------------------------------------------
// bf16 MFMA GEMM, C = A @ W^T.  BM=128, BN=128, BK=64, 512 threads (8 waves,
// wave grid 4x2, each 32 rows x 64 cols). Weights Bw: bf16 [N][K]. A per AMODE:
//   0: plain bf16 rows, stride K (embH / chartH level block / Hh)
//   1: inside concat  [left(cinH) | right(cinH)]      (K=1536)
//   2: outside concat [parent(coutH) | sister(cinH)]  (K=1536)
// EPI 0: bf16(relu(acc+bias)) -> outH ; 1: bf16(acc) -> outH ;
// EPI 2: tanhf(acc+bias) -> outF (f32, word level).
// Rows are pair-major: row = pair*64 + b. Tail (odd pair count) handled by
// clamped gather + guarded store.
// ---------------------------------------------------------------------------
template <int AMODE, int EPI>
__launch_bounds__(512)
__global__ void gemm_k(const unsigned short* __restrict__ Abase,
                       const unsigned short* __restrict__ cinH,
                       const unsigned short* __restrict__ coutH,
                       const unsigned short* __restrict__ Bw,
                       const float* __restrict__ bias,
                       float* __restrict__ outF,
                       unsigned short* __restrict__ outH,
                       int K, int len, int C, int Mrows) {
    __shared__ unsigned short As[128 * 64];   // 16 KB, linear, source-swizzled
    __shared__ unsigned short Bs[128 * 64];   // 16 KB

    const int t = threadIdx.x;
    const int m0 = blockIdx.x << 7;
    const int n0 = blockIdx.y << 7;

    // staging geometry: LDS byte slot p = i*8192 + t*16 ; row = p>>7 ;
    // source column byte = (p&127) ^ ((row&7)<<4)  (swizzle on the source)
    int arow[2], acol[2];
#pragma unroll
    for (int i = 0; i < 2; ++i) {
        const int p = (i << 13) + t * 16;
        const int r = p >> 7;
        arow[i] = r;                                   // 0..127
        acol[i] = ((p & 127) ^ ((r & 7) << 4)) >> 1;   // element offset 0..63
    }

    // A gather bases (per-half pair; row within half == batch index b)
    const unsigned short *aL[2], *aR[2];
    if (AMODE == 1 || AMODE == 2) {
        const int pairs = Mrows >> 6;
#pragma unroll
        for (int i = 0; i < 2; ++i) {
            int p = 2 * blockIdx.x + (arow[i] >> 6);
            p = min(p, pairs - 1);
            const int s = p / C, c = p - s * C;
            int cl, cr;
            if (AMODE == 1) {
                const int j = c + 1;
                cl = lvl_off(j) + s;
                cr = lvl_off(len - j) + s + j;
            } else {
                if (c < s) { cl = lvl_off(len + c + 1) + (s - c - 1); cr = lvl_off(c + 1) + (s - c - 1); }
                else       { cl = lvl_off(len + C - c) + s;           cr = lvl_off(C - c) + (s + len); }
            }
            const int b = arow[i] & 63;
            aL[i] = (AMODE == 1 ? cinH : coutH) + ((size_t)cl * 64 + b) * 768;
            aR[i] = cinH + ((size_t)cr * 64 + b) * 768;
        }
    }

    const int wv = t >> 6, lane = t & 63;
    const int lr = lane & 15, kg = lane >> 4;
    const int wrow = (wv >> 1) << 5;   // 0/32/64/96
    const int wcol = (wv & 1) << 6;    // 0/64

    f32x4 acc[2][4] = {};

    for (int k0 = 0; k0 < K; k0 += 64) {
        // ---- stage A (2 x 8KB) and B (2 x 8KB) via global_load_lds ----
#pragma unroll
        for (int i = 0; i < 2; ++i) {
            const unsigned short* src;
            if (AMODE == 0) {
                const int rsrc = min(m0 + arow[i], Mrows - 1);
                src = Abase + (size_t)rsrc * K + k0 + acol[i];
            } else {
                src = (k0 < 768 ? aL[i] + k0 : aR[i] + (k0 - 768)) + acol[i];
            }
            gload16(src, &As[(i << 12) + t * 8]);
        }
#pragma unroll
        for (int i = 0; i < 2; ++i) {
            const unsigned short* src = Bw + (size_t)(n0 + arow[i]) * K + k0 + acol[i];
            gload16(src, &Bs[(i << 12) + t * 8]);
        }
        __syncthreads();  // drains vmcnt(0): LDS tiles ready

        // ---- MFMA: 2 k-subtiles of 32 ----
#pragma unroll
        for (int kk = 0; kk < 2; ++kk) {
            const int ke = kk * 32 + kg * 8;
            const bf16x8 a0 = *frag_ptr(As, wrow + lr, ke);
            const bf16x8 a1 = *frag_ptr(As, wrow + 16 + lr, ke);
            const bf16x8 b0 = *frag_ptr(Bs, wcol + lr, ke);
            const bf16x8 b1 = *frag_ptr(Bs, wcol + 16 + lr, ke);
            const bf16x8 b2 = *frag_ptr(Bs, wcol + 32 + lr, ke);
            const bf16x8 b3 = *frag_ptr(Bs, wcol + 48 + lr, ke);
            acc[0][0] = __builtin_amdgcn_mfma_f32_16x16x32_bf16(a0, b0, acc[0][0], 0, 0, 0);
            acc[0][1] = __builtin_amdgcn_mfma_f32_16x16x32_bf16(a0, b1, acc[0][1], 0, 0, 0);
            acc[0][2] = __builtin_amdgcn_mfma_f32_16x16x32_bf16(a0, b2, acc[0][2], 0, 0, 0);
            acc[0][3] = __builtin_amdgcn_mfma_f32_16x16x32_bf16(a0, b3, acc[0][3], 0, 0, 0);
            acc[1][0] = __builtin_amdgcn_mfma_f32_16x16x32_bf16(a1, b0, acc[1][0], 0, 0, 0);
            acc[1][1] = __builtin_amdgcn_mfma_f32_16x16x32_bf16(a1, b1, acc[1][1], 0, 0, 0);
            acc[1][2] = __builtin_amdgcn_mfma_f32_16x16x32_bf16(a1, b2, acc[1][2], 0, 0, 0);
            acc[1][3] = __builtin_amdgcn_mfma_f32_16x16x32_bf16(a1, b3, acc[1][3], 0, 0, 0);
        }
        __syncthreads();  // all waves done reading before next stage
    }

    // ---- epilogue: row = m0+wrow+fm*16+kg*4+r, col = n0+wcol+fn*16+lr ----
    float bs[4];
    if (EPI != 1) {
#pragma unroll
        for (int fn = 0; fn < 4; ++fn) bs[fn] = bias[n0 + wcol + fn * 16 + lr];
    }
#pragma unroll
    for (int fm = 0; fm < 2; ++fm) {
#pragma unroll
        for (int fn = 0; fn < 4; ++fn) {
#pragma unroll
            for (int r = 0; r < 4; ++r) {
                const int grow = m0 + wrow + fm * 16 + (kg << 2) + r;
                if (grow >= Mrows) continue;
                const size_t row = (size_t)grow * 768;
                const int col = n0 + wcol + fn * 16 + lr;
                float v = acc[fm][fn][r];
                if (EPI == 0) {
                    outH[row + col] = f2bf(fmaxf(v + bs[fn], 0.f));
                } else if (EPI == 1) {
                    outH[row + col] = f2bf(v);
                } else {
                    outF[row + col] = tanhf(v + bs[fn]);
                }
            }
        }
    }
}

// ---------------------------------------------------------------------------
// Fused score + softmax. Block = one (span s, batch b). 4 waves sweep the C
// contexts (dot(L, U[r]) + child/parent scores -> LDS), then wave 0 does a
// 64-lane butterfly softmax, writes weights + weighted score.
// ---------------------------------------------------------------------------
template <int OUTSIDE>
__launch_bounds__(256)
__global__ void scoresm_k(const unsigned short* __restrict__ cinH,
                          const unsigned short* __restrict__ coutH,
                          const unsigned short* __restrict__ U,
                          const float* __restrict__ isc, const float* __restrict__ osc,
                          float* __restrict__ wbuf, float* __restrict__ cscore,
                          int len, int C) {
    __shared__ float sc[32];
    const int s = blockIdx.x >> 6, b = blockIdx.x & 63;
    const int t = threadIdx.x;
    const int wv = t >> 6, lane = t & 63;

    for (int c = wv; c < C; c += 4) {
        int cl, cr;
        float sadd;
        const unsigned short* L;
        if (!OUTSIDE) {
            const int j = c + 1;
            cl = lvl_off(j) + s;
            cr = lvl_off(len - j) + s + j;
            L = cinH + ((size_t)cl * 64 + b) * 768;
            sadd = isc[cl * 64 + b] + isc[cr * 64 + b];
        } else {
            if (c < s) { cl = lvl_off(len + c + 1) + (s - c - 1); cr = lvl_off(c + 1) + (s - c - 1); }
            else       { cl = lvl_off(len + C - c) + s;           cr = lvl_off(C - c) + (s + len); }
            L = coutH + ((size_t)cl * 64 + b) * 768;
            sadd = osc[cl * 64 + b] + isc[cr * 64 + b];
        }
        const unsigned short* Uv = U + ((size_t)cr * 64 + b) * 768;
        float d = 0.f;
#pragma unroll
        for (int it = 0; it < 3; ++it) {
            const int i = lane * 4 + it * 256;
            ushort4 lv = *reinterpret_cast<const ushort4*>(&L[i]);
            ushort4 uv = *reinterpret_cast<const ushort4*>(&Uv[i]);
            d += bf2f(lv.x) * bf2f(uv.x) + bf2f(lv.y) * bf2f(uv.y) +
                 bf2f(lv.z) * bf2f(uv.z) + bf2f(lv.w) * bf2f(uv.w);
        }
#pragma unroll
        for (int o = 32; o; o >>= 1) d += __shfl_xor(d, o);
        if (lane == 0) sc[c] = d + sadd;
    }
    __syncthreads();

    if (t < 64) {
        const float x = (t < C) ? sc[t] : -1e30f;
        float m = x;
#pragma unroll
        for (int o = 32; o; o >>= 1) m = fmaxf(m, __shfl_xor(m, o));
        const float e = (t < C) ? expf(x - m) : 0.f;
        float sum = e;
#pragma unroll
        for (int o = 32; o; o >>= 1) sum += __shfl_xor(sum, o);
        const float wv2 = e / sum;
        float ws = (t < C) ? wv2 * x : 0.f;
#pragma unroll
        for (int o = 32; o; o >>= 1) ws += __shfl_xor(ws, o);
        if (t < C) wbuf[((s * C + t) << 6) + b] = wv2;
        if (t == 0) cscore[s * 64 + b] = ws;
    }
}

// weighted sum over contexts + L2-normalize -> bf16 chart level block.
// 192 active lanes x ushort4 (768 elems).
__launch_bounds__(256)
__global__ void reduce_norm_k(const unsigned short* __restrict__ V,
                              const float* __restrict__ w,
                              unsigned short* __restrict__ outvH, int C) {
    __shared__ float red[256];
    const int sb = blockIdx.x;
    const int s = sb >> 6, b = sb & 63;
    const int t = threadIdx.x;
    float a0 = 0.f, a1 = 0.f, a2 = 0.f, a3 = 0.f;
    const int e = t * 4;
    for (int c = 0; c < C; ++c) {
        const int rowi = ((s * C + c) << 6) + b;
        const float wv = w[rowi];
        if (t < 192) {
            ushort4 v = *reinterpret_cast<const ushort4*>(&V[(size_t)rowi * 768 + e]);
            a0 += wv * bf2f(v.x);
            a1 += wv * bf2f(v.y);
            a2 += wv * bf2f(v.z);
            a3 += wv * bf2f(v.w);
        }
    }
    red[t] = (t < 192) ? (a0 * a0 + a1 * a1 + a2 * a2 + a3 * a3) : 0.f;
    __syncthreads();
    for (int o = 128; o; o >>= 1) {
        if (t < o) red[t] += red[t + o];
        __syncthreads();
    }
    const float scale = 1.f / fmaxf(sqrtf(red[0]), 1e-12f);
    if (t < 192) {
        ushort4 ov;
        ov.x = f2bf(a0 * scale);
        ov.y = f2bf(a1 * scale);
        ov.z = f2bf(a2 * scale);
        ov.w = f2bf(a3 * scale);
        *reinterpret_cast<ushort4*>(&outvH[(size_t)sb * 768 + e]) = ov;
    }
}

// row L2-normalize f32 src -> bf16 dst (word level)
__launch_bounds__(256)
__global__ void norm_rows_k(const float* __restrict__ src,
                            unsigned short* __restrict__ dstH) {
    __shared__ float red[256];
    const float* p = src + (size_t)blockIdx.x * 768;
    const int t = threadIdx.x;
    const float a0 = p[t], a1 = p[t + 256], a2 = p[t + 512];
    red[t] = a0 * a0 + a1 * a1 + a2 * a2;
    __syncthreads();
    for (int o = 128; o; o >>= 1) {
        if (t < o) red[t] += red[t + o];
        __syncthreads();
    }
    const float scale = 1.f / fmaxf(sqrtf(red[0]), 1e-12f);
    unsigned short* d = dstH + (size_t)blockIdx.x * 768;
    d[t] = f2bf(a0 * scale);
    d[t + 256] = f2bf(a1 * scale);
    d[t + 512] = f2bf(a2 * scale);
}

// root cell: normalize(root_bias) broadcast over batch (bf16).
__launch_bounds__(256)
__global__ void root_k(const float* __restrict__ rb,
                       unsigned short* __restrict__ coutH) {
    __shared__ float red[256];
    const int t = threadIdx.x;
    const float a0 = rb[t], a1 = rb[t + 256], a2 = rb[t + 512];
    red[t] = a0 * a0 + a1 * a1 + a2 * a2;
    __syncthreads();
    for (int o = 128; o; o >>= 1) {
        if (t < o) red[t] += red[t + o];
        __syncthreads();
    }
    const float scale = 1.f / fmaxf(sqrtf(red[0]), 1e-12f);
    const unsigned short v0 = f2bf(a0 * scale), v1 = f2bf(a1 * scale),
                         v2 = f2bf(a2 * scale);
    for (int b = 0; b < 64; ++b) {
        unsigned short* o = coutH + ((size_t)(527 * 64 + b)) * 768;
        o[t] = v0; o[t + 256] = v1; o[t + 512] = v2;
    }
}

__launch_bounds__(256)
__global__ void cvt_bf16_k(const float* __restrict__ src,
                           unsigned short* __restrict__ dst, int n) {
    const int i = blockIdx.x * 256 + threadIdx.x;
    if (i < n) dst[i] = f2bf(src[i]);
}

// out[cell][b] = [in_vec(768) | out_vec(768) | in_score | out_score]
__launch_bounds__(256)
__global__ void assemble_k(const unsigned short* __restrict__ cinH,
                           const unsigned short* __restrict__ coutH,
                           const float* __restrict__ isc, const float* __restrict__ osc,
                           float* __restrict__ out) {
    const int sb = blockIdx.x;
    const int t = threadIdx.x;
    const unsigned short* iv = cinH + (size_t)sb * 768;
    const unsigned short* ov = coutH + (size_t)sb * 768;
    float* o = out + (size_t)sb * 1538;
    o[t] = bf2f(iv[t]); o[t + 256] = bf2f(iv[t + 256]); o[t + 512] = bf2f(iv[t + 512]);
    o[768 + t] = bf2f(ov[t]); o[768 + t + 256] = bf2f(ov[t + 256]);
    o[768 + t + 512] = bf2f(ov[t + 512]);
    if (t == 0) { o[1536] = isc[sb]; o[1537] = osc[sb]; }
}

// ---------------------------------------------------------------------------
extern "C" void kernel_launch(void* const* d_in, const int* in_sizes, int n_in,
                              void* d_out, int out_size, void* d_ws, size_t ws_size,
                              hipStream_t stream) {
    const float* emb = (const float*)d_in[0];
    const float* Wl = (const float*)d_in[1];
    const float* bl = (const float*)d_in[2];
    const float* W1 = (const float*)d_in[3];
    const float* b1 = (const float*)d_in[4];
    const float* W2 = (const float*)d_in[5];
    const float* b2 = (const float*)d_in[6];
    const float* Wb = (const float*)d_in[7];
    const float* rb = (const float*)d_in[8];
    float* out = (float*)d_out;

    char* ws = (char*)d_ws;
    size_t off = 0;
    auto alloc = [&](size_t bytes) {
        char* p = ws + off;
        off = (off + bytes + 255) & ~(size_t)255;
        return p;
    };
    unsigned short* cinH = (unsigned short*)alloc((size_t)TRI * 64 * 768 * 2);
    unsigned short* coutH = (unsigned short*)alloc((size_t)TRI * 64 * 768 * 2);
    unsigned short* Uh = (unsigned short*)alloc((size_t)TRI * 64 * 768 * 2);
    unsigned short* Hh = (unsigned short*)alloc((size_t)MAXM * 768 * 2);
    unsigned short* Vh = (unsigned short*)alloc((size_t)MAXM * 768 * 2);
    unsigned short* embH = (unsigned short*)alloc((size_t)2048 * 768 * 2);
    float* chart_is = (float*)alloc((size_t)TRI * 64 * 4);
    float* chart_os = (float*)alloc((size_t)TRI * 64 * 4);
    float* wbuf = (float*)alloc((size_t)MAXM * 4);
    unsigned short* Wlh = (unsigned short*)alloc((size_t)768 * 768 * 2);
    unsigned short* W1h = (unsigned short*)alloc((size_t)768 * 1536 * 2);
    unsigned short* W2h = (unsigned short*)alloc((size_t)768 * 768 * 2);
    unsigned short* Wbh = (unsigned short*)alloc((size_t)768 * 768 * 2);
    float* tmpF = (float*)Hh;  // word-level tanh temp (f32 view, 6MB < Hh)

    cvt_bf16_k<<<(768 * 768 + 255) / 256, 256, 0, stream>>>(Wl, Wlh, 768 * 768);
    cvt_bf16_k<<<(768 * 1536 + 255) / 256, 256, 0, stream>>>(W1, W1h, 768 * 1536);
    cvt_bf16_k<<<(768 * 768 + 255) / 256, 256, 0, stream>>>(W2, W2h, 768 * 768);
    cvt_bf16_k<<<(768 * 768 + 255) / 256, 256, 0, stream>>>(Wb, Wbh, 768 * 768);
    cvt_bf16_k<<<(2048 * 768 + 255) / 256, 256, 0, stream>>>(emb, embH, 2048 * 768);
    hipMemsetAsync(chart_is, 0, (size_t)TRI * 64 * 4, stream);
    hipMemsetAsync(chart_os, 0, (size_t)TRI * 64 * 4, stream);

    // word level: tanh(emb @ Wl^T + bl) -> f32 tmp -> normalize -> bf16 chart
    gemm_k<0, 2><<<dim3(16, 6), 512, 0, stream>>>(
        embH, nullptr, nullptr, Wlh, bl, tmpF, nullptr, 768, 0, 0, 2048);
    norm_rows_k<<<2048, 256, 0, stream>>>(tmpF, cinH);
    gemm_k<0, 1><<<dim3(16, 6), 512, 0, stream>>>(
        cinH, nullptr, nullptr, Wbh, nullptr, nullptr, Uh, 768, 0, 0, 2048);

    // ---------------- inside pass ----------------
    for (int len = 2; len <= 32; ++len) {
        const int S = 33 - len, C = len - 1;
        const int pairs = S * C, M = pairs * 64;
        const size_t lo = (size_t)lvl_off(len);
        scoresm_k<0><<<S * 64, 256, 0, stream>>>(cinH, nullptr, Uh, chart_is, nullptr,
                                                 wbuf, chart_is + lo * 64, len, C);
        gemm_k<1, 0><<<dim3((pairs + 1) / 2, 6), 512, 0, stream>>>(
            nullptr, cinH, nullptr, W1h, b1, nullptr, Hh, 1536, len, C, M);
        gemm_k<0, 0><<<dim3((pairs + 1) / 2, 6), 512, 0, stream>>>(
            Hh, nullptr, nullptr, W2h, b2, nullptr, Vh, 768, 0, 0, M);
        reduce_norm_k<<<S * 64, 256, 0, stream>>>(Vh, wbuf, cinH + lo * 64 * 768, C);
        gemm_k<0, 1><<<dim3((S + 1) / 2, 6), 512, 0, stream>>>(
            cinH + lo * 64 * 768, nullptr, nullptr, Wbh, nullptr, nullptr,
            Uh + lo * 64 * 768, 768, 0, 0, S * 64);
    }

    // ---------------- outside pass ----------------
    root_k<<<1, 256, 0, stream>>>(rb, coutH);
    for (int len = 31; len >= 1; --len) {
        const int S = 33 - len, C = 32 - len;
        const int pairs = S * C, M = pairs * 64;
        const size_t lo = (size_t)lvl_off(len);
        scoresm_k<1><<<S * 64, 256, 0, stream>>>(cinH, coutH, Uh, chart_is, chart_os,
                                                 wbuf, chart_os + lo * 64, len, C);
        gemm_k<2, 0><<<dim3((pairs + 1) / 2, 6), 512, 0, stream>>>(
            nullptr, cinH, coutH, W1h, b1, nullptr, Hh, 1536, len, C, M);
        gemm_k<0, 0><<<dim3((pairs + 1) / 2, 6), 512, 0, stream>>>(
            Hh, nullptr, nullptr, W2h, b2, nullptr, Vh, 768, 0, 0, M);
        reduce_norm_k<<<S * 64, 256, 0, stream>>>(Vh, wbuf, coutH + lo * 64 * 768, C);
    }

    assemble_k<<<TRI * 64, 256, 0, stream>>>(cinH, coutH, chart_is, chart_os, out);
}